// Round 5
// baseline (520.863 us; speedup 1.0000x reference)
//
#include <hip/hip_runtime.h>
#include <hip/hip_fp16.h>
#include <cstdint>
#include <cstddef>

typedef _Float16 f16;
typedef __attribute__((ext_vector_type(4))) _Float16 f16x4;
typedef __attribute__((ext_vector_type(8))) _Float16 f16x8;
typedef __attribute__((ext_vector_type(4))) float f32x4;

#define C_INV_SQRT2 0.70710678118654752440f

__device__ __forceinline__ void gld_lds16(const void* g, void* l) {
  __builtin_amdgcn_global_load_lds((const __attribute__((address_space(1))) void*)g,
                                   (__attribute__((address_space(3))) void*)l, 16, 0, 0);
}

// ---------------- conversion kernels ----------------
__global__ __launch_bounds__(256) void cvt_f32_f16_k(const float* __restrict__ in,
                                                     f16* __restrict__ out, int n4) {
  int i = blockIdx.x * 256 + threadIdx.x;
  if (i >= n4) return;
  const float4 x = ((const float4*)in)[i];
  f16x4 y;
  y.x = (f16)x.x; y.y = (f16)x.y; y.z = (f16)x.z; y.w = (f16)x.w;
  ((f16x4*)out)[i] = y;
}

// pack W_qkv rows {0..1023} and {2048..3071} into Wo[2048][1024] f16; same for bias
__global__ __launch_bounds__(256) void pack_wqv_k(const float* __restrict__ W,
                                                  const float* __restrict__ b,
                                                  f16* __restrict__ Wo,
                                                  float* __restrict__ bo) {
  int i = blockIdx.x * 256 + threadIdx.x;
  int n = i >> 8;
  int c = (i & 255) * 4;
  int sn = (n < 1024) ? n : (n + 1024);
  const float4 x = *(const float4*)(W + (size_t)sn * 1024 + c);
  f16x4 y; y.x = (f16)x.x; y.y = (f16)x.y; y.z = (f16)x.z; y.w = (f16)x.w;
  *(f16x4*)(Wo + (size_t)n * 1024 + c) = y;
  if (i < 2048) bo[i] = b[(i < 1024) ? i : (i + 1024)];
}

// ---- 256x256 GEMM, 4 waves x 128x128/wave, frag read-ahead pipeline ----
// C[M,N] = A[M,K]*B[N,K]^T + bias.  256 threads = 4 waves (2M x 2N).
// Sub-tile BK=32; 4 LDS buffers (128 KiB); stage-ahead-3, vmcnt(8) steady.
// Segment s: vmcnt(8) [stage(s+1) landed] -> barrier -> STAGE(s+3) ->
//   16 ds_read_b128 frags(s+1) into NXT regs -> 64 MFMA on CUR regs
//   (compiler lgkmcnt(16) waits only CUR's reads; NXT service hides under MFMA).
// LDS chunk-XOR swizzle chunk^((row>>1)&3), both-sides.  XCD swizzle (nwg%8==0).

#define STAGE4(bufi, k0)                                      \
  {                                                           \
    _Pragma("unroll") for (int i = 0; i < 4; i++)             \
        gld_lds16(pGA[i] + (k0), &lds[bufi][0][0] + dstL[i]); \
    _Pragma("unroll") for (int i = 0; i < 4; i++)             \
        gld_lds16(pGB[i] + (k0), &lds[bufi][1][0] + dstL[i]); \
  }

#define READF(aF, bF, bufi)                                                  \
  {                                                                          \
    const f16* pA_ = &lds[bufi][0][0] + Abase;                               \
    const f16* pB_ = &lds[bufi][1][0] + Bbase;                               \
    _Pragma("unroll") for (int mi = 0; mi < 8; mi++)                         \
        aF[mi] = *(const f16x8*)(pA_ + mi * 512);                            \
    _Pragma("unroll") for (int nj = 0; nj < 8; nj++)                         \
        bF[nj] = *(const f16x8*)(pB_ + nj * 512);                            \
  }

#define MFMA64(aF, bF)                                                       \
  {                                                                          \
    __builtin_amdgcn_s_setprio(1);                                           \
    _Pragma("unroll") for (int mi = 0; mi < 8; mi++)                         \
        _Pragma("unroll") for (int nj = 0; nj < 8; nj++)                     \
            acc[mi][nj] = __builtin_amdgcn_mfma_f32_16x16x32_f16(            \
                aF[mi], bF[nj], acc[mi][nj], 0, 0, 0);                       \
    __builtin_amdgcn_s_setprio(0);                                           \
  }

#define ITER(s, aC, bC, aN, bN)                                      \
  {                                                                  \
    if ((s) < NS - 2) {                                              \
      asm volatile("s_waitcnt vmcnt(8)" ::: "memory");               \
    } else if ((s) == NS - 2) {                                      \
      asm volatile("s_waitcnt vmcnt(0)" ::: "memory");               \
    }                                                                \
    __builtin_amdgcn_sched_barrier(0);                               \
    __builtin_amdgcn_s_barrier();                                    \
    __builtin_amdgcn_sched_barrier(0);                               \
    if ((s) + 3 < NS) STAGE4(((s) + 3) & 3, ((s) + 3) * 32);         \
    if ((s) + 1 < NS) READF(aN, bN, ((s) + 1) & 3);                  \
    __builtin_amdgcn_sched_barrier(0);                               \
    MFMA64(aC, bC);                                                  \
  }

template <typename CT>
__global__ __launch_bounds__(256, 1) void gemm256_k(const f16* __restrict__ A,
                                                    const f16* __restrict__ B,
                                                    const float* __restrict__ bias,
                                                    CT* __restrict__ C,
                                                    int M, int N, int K, int nbx) {
  __shared__ f16 lds[4][2][256 * 32];  // [buf][A/B][256 rows x 32 f16] = 128 KiB
  const int t = threadIdx.x;
  const int w = t >> 6, l = t & 63;
  const int wm = w >> 1, wn = w & 1;  // 2 x 2 wave grid, 128x128 per wave
  const int hi = l >> 4, lo = l & 15;

  // T1: bijective XCD swizzle
  const int nwg = gridDim.x;
  const int cpx = nwg >> 3;
  const int bid = blockIdx.x;
  const int nid = (bid & 7) * cpx + (bid >> 3);
  const int by = nid / nbx, bx = nid - by * nbx;
  const int m0 = by * 256, n0 = bx * 256;

  const f16* GA = A + (size_t)m0 * K;
  const f16* GB = B + (size_t)n0 * K;

  // staging: thread covers 16B slots u = i*256 + t (i=0..3) of a [256 row][4 chunk]
  // plane; slot u holds global (row = u>>2, chunk = (u&3) ^ ((u>>3)&3))
  const f16* pGA[4];
  const f16* pGB[4];
  int dstL[4];
#pragma unroll
  for (int i = 0; i < 4; i++) {
    const int u = i * 256 + t;
    const int row = u >> 2;
    const int ch = (u & 3) ^ ((u >> 3) & 3);
    pGA[i] = GA + (size_t)row * K + ch * 8;
    pGB[i] = GB + (size_t)row * K + ch * 8;
    dstL[i] = (i * 256 + w * 64) * 8;
  }

  // read-side swizzled bases: swz term (r>>1)&3 == (lo>>1)&3 (frag-independent)
  const int swz = (hi ^ ((lo >> 1) & 3)) << 3;
  const int Abase = (wm * 128 + lo) * 32 + swz;
  const int Bbase = (wn * 128 + lo) * 32 + swz;

  f32x4 acc[8][8] = {};
  f16x8 aP[8], bP[8], aQ[8], bQ[8];
  const int NS = K >> 5;  // even (K=1024 -> 32)

  STAGE4(0, 0);
  STAGE4(1, 32);
  STAGE4(2, 64);
  asm volatile("s_waitcnt vmcnt(16)" ::: "memory");
  __builtin_amdgcn_s_barrier();
  __builtin_amdgcn_sched_barrier(0);
  READF(aP, bP, 0);

  for (int s = 0; s < NS; s += 2) {
    ITER(s, aP, bP, aQ, bQ);
    ITER(s + 1, aQ, bQ, aP, bP);
  }

  // epilogue: C/D layout col = lane&15, row = (lane>>4)*4 + reg
#pragma unroll
  for (int mi = 0; mi < 8; mi++) {
#pragma unroll
    for (int nj = 0; nj < 8; nj++) {
      const int col = n0 + wn * 128 + nj * 16 + lo;
      const float bb = bias[col];
      const size_t base = (size_t)(m0 + wm * 128 + mi * 16 + hi * 4) * N + col;
#pragma unroll
      for (int r = 0; r < 4; r++) C[base + (size_t)r * N] = (CT)(acc[mi][nj][r] + bb);
    }
  }
}

// ---------------- fused wavelet middle (vectorized f16x4 loads) ----------------
// qv: [32768][2048] f16 (cols 0..1023 = q, 1024..2047 = v), out: [32768][1024] f16
__global__ __launch_bounds__(256) void dwt_middle_k(const f16* __restrict__ qv,
                                                    const float* __restrict__ wq,
                                                    const float* __restrict__ wv,
                                                    f16* __restrict__ out) {
  const int g = blockIdx.x;        // row-group (8 rows), 0..4095
  const int d0 = threadIdx.x * 4;  // 4 consecutive d per thread
  const size_t m0 = (size_t)g * 8;

  f16x4 qr[8], vr[8], o[8];
#pragma unroll
  for (int i = 0; i < 8; i++) {
    qr[i] = *(const f16x4*)(qv + (m0 + i) * 2048 + d0);
    vr[i] = *(const f16x4*)(qv + (m0 + i) * 2048 + 1024 + d0);
  }
  const float c = C_INV_SQRT2;
#pragma unroll
  for (int dd = 0; dd < 4; dd++) {
    const int d = d0 + dd;
    const int h = d >> 6, dh = d & 63;
    float q[8], v[8];
#pragma unroll
    for (int i = 0; i < 8; i++) { q[i] = (float)qr[i][dd]; v[i] = (float)vr[i][dd]; }

    float qa1[4], qd1[4], va1[4], vd1[4];
#pragma unroll
    for (int i = 0; i < 4; i++) {
      qd1[i] = (q[2 * i] - q[2 * i + 1]) * c;
      qa1[i] = (q[2 * i] + q[2 * i + 1]) * c;
      vd1[i] = (v[2 * i] - v[2 * i + 1]) * c;
      va1[i] = (v[2 * i] + v[2 * i + 1]) * c;
    }
    float qa2[2], qd2[2], va2[2], vd2[2];
#pragma unroll
    for (int j = 0; j < 2; j++) {
      qd2[j] = (qa1[2 * j] - qa1[2 * j + 1]) * c;
      qa2[j] = (qa1[2 * j] + qa1[2 * j + 1]) * c;
      vd2[j] = (va1[2 * j] - va1[2 * j + 1]) * c;
      va2[j] = (va1[2 * j] + va1[2 * j + 1]) * c;
    }
    const float qd3 = (qa2[0] - qa2[1]) * c, qa3 = (qa2[0] + qa2[1]) * c;
    const float vd3 = (va2[0] - va2[1]) * c, va3 = (va2[0] + va2[1]) * c;

    const int wb = h * 192 + dh;
    const float wq0 = wq[wb], wq1 = wq[wb + 64], wq2 = wq[wb + 128];
    const float wv0 = wv[wb], wv1 = wv[wb + 64], wv2 = wv[wb + 128];

    const float pa = (qa3 * wq0) * (va3 * wv0);
    const float pd3 = (qd3 * wq1) * (vd3 * wv1);
    float pd2[2], pd1[4];
#pragma unroll
    for (int j = 0; j < 2; j++) pd2[j] = (qd2[j] * wq2) * (vd2[j] * wv2);
#pragma unroll
    for (int i = 0; i < 4; i++) pd1[i] = qd1[i] * vd1[i];

    float s2[2], s1[4];
    s2[0] = (pa + pd3) * c;
    s2[1] = (pa - pd3) * c;
#pragma unroll
    for (int j = 0; j < 2; j++) {
      s1[2 * j] = (s2[j] + pd2[j]) * c;
      s1[2 * j + 1] = (s2[j] - pd2[j]) * c;
    }
#pragma unroll
    for (int i = 0; i < 4; i++) {
      o[2 * i][dd] = (f16)((s1[i] + pd1[i]) * c);
      o[2 * i + 1][dd] = (f16)((s1[i] - pd1[i]) * c);
    }
  }
#pragma unroll
  for (int i = 0; i < 8; i++) *(f16x4*)(out + (m0 + i) * 1024 + d0) = o[i];
}

// ---------------- launch ----------------
extern "C" void kernel_launch(void* const* d_in, const int* in_sizes, int n_in,
                              void* d_out, int out_size, void* d_ws, size_t ws_size,
                              hipStream_t stream) {
  (void)in_sizes; (void)n_in; (void)out_size; (void)ws_size;
  const float* query = (const float*)d_in[0];
  const float* W_qkv = (const float*)d_in[1];
  const float* b_qkv = (const float*)d_in[2];
  const float* W_out = (const float*)d_in[3];
  const float* b_out = (const float*)d_in[4];
  const float* wq = (const float*)d_in[5];
  const float* wv = (const float*)d_in[6];
  float* out = (float*)d_out;

  // workspace layout
  char* ws = (char*)d_ws;
  f16* qf16 = (f16*)ws;                                // 67,108,864 B (reused as a_f16)
  f16* Wqv = (f16*)(ws + 67108864);                    //  4,194,304 B
  float* bqv = (float*)(ws + 67108864 + 4194304);      //      8,192 B
  f16* Wout = (f16*)(ws + 67108864 + 4194304 + 8192);  //  2,097,152 B
  f16* qv = (f16*)d_out;  // qv intermediate lives in d_out (exactly out bytes)
  f16* a_f16 = qf16;      // alias: qf16 dead after GEMM1

  // 1. query -> f16
  cvt_f32_f16_k<<<dim3(8388608 / 256), dim3(256), 0, stream>>>(query, qf16, 8388608);
  // 2. pack W_qv + bias
  pack_wqv_k<<<dim3(2048), dim3(256), 0, stream>>>(W_qkv, b_qkv, Wqv, bqv);
  // 3. W_out -> f16
  cvt_f32_f16_k<<<dim3(262144 / 256), dim3(256), 0, stream>>>(W_out, Wout, 262144);
  // 4. GEMM1: qv[32768,2048] = query_f16 * Wqv^T + bqv   (grid 1024 blocks)
  gemm256_k<f16><<<dim3((2048 / 256) * (32768 / 256)), dim3(256), 0, stream>>>(
      qf16, Wqv, bqv, qv, 32768, 2048, 1024, 2048 / 256);
  // 5. fused wavelet middle: a[32768,1024] f16
  dwt_middle_k<<<dim3(4096), dim3(256), 0, stream>>>(qv, wq, wv, a_f16);
  // 6. GEMM2: out = a * Wout^T + b_out (fp32)   (grid 512 blocks)
  gemm256_k<float><<<dim3((1024 / 256) * (32768 / 256)), dim3(256), 0, stream>>>(
      a_f16, Wout, b_out, out, 32768, 1024, 1024, 1024 / 256);
}

// Round 6
// 325.180 us; speedup vs baseline: 1.6018x; 1.6018x over previous
//
#include <hip/hip_runtime.h>
#include <hip/hip_fp16.h>
#include <cstdint>
#include <cstddef>

typedef _Float16 f16;
typedef __attribute__((ext_vector_type(4))) _Float16 f16x4;
typedef __attribute__((ext_vector_type(8))) _Float16 f16x8;
typedef __attribute__((ext_vector_type(4))) float f32x4;
typedef __attribute__((ext_vector_type(16))) float f32x16;

#define C_INV_SQRT2 0.70710678118654752440f

__device__ __forceinline__ void gld_lds16(const void* g, void* l) {
  __builtin_amdgcn_global_load_lds((const __attribute__((address_space(1))) void*)g,
                                   (__attribute__((address_space(3))) void*)l, 16, 0, 0);
}

// ---------------- conversion kernels ----------------
__global__ __launch_bounds__(256) void cvt_f32_f16_k(const float* __restrict__ in,
                                                     f16* __restrict__ out, int n4) {
  int i = blockIdx.x * 256 + threadIdx.x;
  if (i >= n4) return;
  const float4 x = ((const float4*)in)[i];
  f16x4 y;
  y.x = (f16)x.x; y.y = (f16)x.y; y.z = (f16)x.z; y.w = (f16)x.w;
  ((f16x4*)out)[i] = y;
}

// pack W_qkv rows {0..1023} and {2048..3071} into Wo[2048][1024] f16; same for bias
__global__ __launch_bounds__(256) void pack_wqv_k(const float* __restrict__ W,
                                                  const float* __restrict__ b,
                                                  f16* __restrict__ Wo,
                                                  float* __restrict__ bo) {
  int i = blockIdx.x * 256 + threadIdx.x;
  int n = i >> 8;
  int c = (i & 255) * 4;
  int sn = (n < 1024) ? n : (n + 1024);
  const float4 x = *(const float4*)(W + (size_t)sn * 1024 + c);
  f16x4 y; y.x = (f16)x.x; y.y = (f16)x.y; y.z = (f16)x.z; y.w = (f16)x.w;
  *(f16x4*)(Wo + (size_t)n * 1024 + c) = y;
  if (i < 2048) bo[i] = b[(i < 1024) ? i : (i + 1024)];
}

// ---- 256x256 GEMM: 4 waves x 128x128/wave, 32x32x16 MFMA, acc forced to AGPR ----
// C[M,N] = A[M,K]*B[N,K]^T + bias.  256 threads = 4 waves (2M x 2N).
// BK=32; 4 LDS buffers (128 KiB); stage-ahead-3; vmcnt(8) steady (never 0 in-loop).
// Segment s: vmcnt(8) [stage(s+1) landed] -> barrier -> STAGE(s+3) ->
//   16 ds_read_b128 frags(s+1) into NXT set -> 32 asm MFMA on CUR set (AGPR acc,
//   no lgkm dep -> MFMAs run while NXT reads are serviced).
// LDS slot-XOR swizzle slot^((row>>1)&3) (both-sides, R3-verified 0 conflicts).
// T1 bijective XCD swizzle (nwg % 8 == 0).

#define MFMA_A(accv, a, b)                                          \
  asm("v_mfma_f32_32x32x16_f16 %0, %1, %2, %0"                      \
      : "+a"(accv)                                                  \
      : "v"(a), "v"(b))

#define STAGE4(bufi, k0)                                      \
  {                                                           \
    _Pragma("unroll") for (int i = 0; i < 4; i++)             \
        gld_lds16(pGA[i] + (k0), &lds[bufi][0][0] + dstL[i]); \
    _Pragma("unroll") for (int i = 0; i < 4; i++)             \
        gld_lds16(pGB[i] + (k0), &lds[bufi][1][0] + dstL[i]); \
  }

#define READF(aF, bF, bufi)                                         \
  {                                                                 \
    const f16* pA_ = &lds[bufi][0][0];                              \
    const f16* pB_ = &lds[bufi][1][0];                              \
    _Pragma("unroll") for (int mi = 0; mi < 4; mi++) {              \
      aF[mi][0] = *(const f16x8*)(pA_ + Abase0 + mi * 1024);        \
      aF[mi][1] = *(const f16x8*)(pA_ + Abase1 + mi * 1024);        \
    }                                                               \
    _Pragma("unroll") for (int nj = 0; nj < 4; nj++) {              \
      bF[nj][0] = *(const f16x8*)(pB_ + Bbase0 + nj * 1024);        \
      bF[nj][1] = *(const f16x8*)(pB_ + Bbase1 + nj * 1024);        \
    }                                                               \
  }

#define MFMA32(aF, bF)                                              \
  {                                                                 \
    _Pragma("unroll") for (int mi = 0; mi < 4; mi++)                \
        _Pragma("unroll") for (int nj = 0; nj < 4; nj++) {          \
      MFMA_A(acc[mi][nj], aF[mi][0], bF[nj][0]);                    \
      MFMA_A(acc[mi][nj], aF[mi][1], bF[nj][1]);                    \
    }                                                               \
  }

#define ITER(s, CURa, CURb, NXTa, NXTb)                              \
  {                                                                  \
    if ((s) <= NS - 3) {                                             \
      asm volatile("s_waitcnt vmcnt(8)" ::: "memory");               \
    } else if ((s) == NS - 2) {                                      \
      asm volatile("s_waitcnt vmcnt(0)" ::: "memory");               \
    }                                                                \
    __builtin_amdgcn_sched_barrier(0);                               \
    __builtin_amdgcn_s_barrier();                                    \
    __builtin_amdgcn_sched_barrier(0);                               \
    if ((s) + 3 < NS) STAGE4(((s) + 3) & 3, ((s) + 3) * 32);         \
    if ((s) + 1 < NS) READF(NXTa, NXTb, ((s) + 1) & 3);              \
    MFMA32(CURa, CURb);                                              \
  }

template <typename CT>
__global__ __launch_bounds__(256, 1) void gemm256_k(const f16* __restrict__ A,
                                                    const f16* __restrict__ B,
                                                    const float* __restrict__ bias,
                                                    CT* __restrict__ C,
                                                    int M, int N, int K, int nbx) {
  __shared__ f16 lds[4][2][256 * 32];  // [buf][A/B][256 rows x 32 f16] = 128 KiB
  const int t = threadIdx.x;
  const int w = t >> 6, l = t & 63;
  const int wm = w >> 1, wn = w & 1;  // 2 x 2 wave grid, 128x128 per wave
  const int l31 = l & 31, half = l >> 5;

  // T1: bijective XCD swizzle
  const int nwg = gridDim.x;
  const int cpx = nwg >> 3;
  const int bid = blockIdx.x;
  const int nid = (bid & 7) * cpx + (bid >> 3);
  const int by = nid / nbx, bx = nid - by * nbx;
  const int m0 = by * 256, n0 = bx * 256;

  const f16* GA = A + (size_t)m0 * K;
  const f16* GB = B + (size_t)n0 * K;

  // staging: thread covers 16B slots u = i*256 + t (i=0..3) of a [256 row][4 slot]
  // plane; slot u holds global (row = u>>2, chunk = (u&3) ^ ((u>>3)&3))
  const f16* pGA[4];
  const f16* pGB[4];
  int dstL[4];
#pragma unroll
  for (int i = 0; i < 4; i++) {
    const int u = i * 256 + t;
    const int row = u >> 2;
    const int ch = (u & 3) ^ ((u >> 3) & 3);
    pGA[i] = GA + (size_t)row * K + ch * 8;
    pGB[i] = GB + (size_t)row * K + ch * 8;
    dstL[i] = (i * 256 + w * 64) * 8;
  }

  // read-side swizzled bases (f16 units within one [256][32] plane)
  // frag (mi,ks): row r = wm*128 + mi*32 + l31; slot = (ks*2 + half) ^ ((r>>1)&3)
  // (r>>1)&3 == (l31>>1)&3  (mi*32, wm*128 don't touch bits 1..2)
  const int sw = (l31 >> 1) & 3;
  const int Abase0 = (wm * 128 + l31) * 32 + (((0 + half) ^ sw) << 3);
  const int Abase1 = (wm * 128 + l31) * 32 + (((2 + half) ^ sw) << 3);
  const int Bbase0 = (wn * 128 + l31) * 32 + (((0 + half) ^ sw) << 3);
  const int Bbase1 = (wn * 128 + l31) * 32 + (((2 + half) ^ sw) << 3);

  f32x16 acc[4][4] = {};           // 256 f32 -> AGPR (forced by "+a" in MFMA_A)
  f16x8 aP[4][2], bP[4][2], aQ[4][2], bQ[4][2];
  const int NS = K >> 5;  // K=1024 -> 32 (even)

  STAGE4(0, 0);
  STAGE4(1, 32);
  STAGE4(2, 64);
  asm volatile("s_waitcnt vmcnt(16)" ::: "memory");
  __builtin_amdgcn_s_barrier();
  __builtin_amdgcn_sched_barrier(0);
  READF(aP, bP, 0);

  for (int s = 0; s < NS; s += 2) {
    ITER(s, aP, bP, aQ, bQ);
    ITER(s + 1, aQ, bQ, aP, bP);
  }

  // epilogue: 32x32 C/D layout col = lane&31, row = (reg&3) + 8*(reg>>2) + 4*half
#pragma unroll
  for (int mi = 0; mi < 4; mi++) {
#pragma unroll
    for (int nj = 0; nj < 4; nj++) {
      const int col = n0 + wn * 128 + nj * 32 + l31;
      const float bb = bias[col];
      const int rbase = m0 + wm * 128 + mi * 32 + 4 * half;
#pragma unroll
      for (int r = 0; r < 16; r++) {
        const int row = rbase + (r & 3) + 8 * (r >> 2);
        C[(size_t)row * N + col] = (CT)(acc[mi][nj][r] + bb);
      }
    }
  }
}

// ---------------- fused wavelet middle (vectorized f16x4 loads) ----------------
// qv: [32768][2048] f16 (cols 0..1023 = q, 1024..2047 = v), out: [32768][1024] f16
__global__ __launch_bounds__(256) void dwt_middle_k(const f16* __restrict__ qv,
                                                    const float* __restrict__ wq,
                                                    const float* __restrict__ wv,
                                                    f16* __restrict__ out) {
  const int g = blockIdx.x;        // row-group (8 rows), 0..4095
  const int d0 = threadIdx.x * 4;  // 4 consecutive d per thread
  const size_t m0 = (size_t)g * 8;

  f16x4 qr[8], vr[8], o[8];
#pragma unroll
  for (int i = 0; i < 8; i++) {
    qr[i] = *(const f16x4*)(qv + (m0 + i) * 2048 + d0);
    vr[i] = *(const f16x4*)(qv + (m0 + i) * 2048 + 1024 + d0);
  }
  const float c = C_INV_SQRT2;
#pragma unroll
  for (int dd = 0; dd < 4; dd++) {
    const int d = d0 + dd;
    const int h = d >> 6, dh = d & 63;
    float q[8], v[8];
#pragma unroll
    for (int i = 0; i < 8; i++) { q[i] = (float)qr[i][dd]; v[i] = (float)vr[i][dd]; }

    float qa1[4], qd1[4], va1[4], vd1[4];
#pragma unroll
    for (int i = 0; i < 4; i++) {
      qd1[i] = (q[2 * i] - q[2 * i + 1]) * c;
      qa1[i] = (q[2 * i] + q[2 * i + 1]) * c;
      vd1[i] = (v[2 * i] - v[2 * i + 1]) * c;
      va1[i] = (v[2 * i] + v[2 * i + 1]) * c;
    }
    float qa2[2], qd2[2], va2[2], vd2[2];
#pragma unroll
    for (int j = 0; j < 2; j++) {
      qd2[j] = (qa1[2 * j] - qa1[2 * j + 1]) * c;
      qa2[j] = (qa1[2 * j] + qa1[2 * j + 1]) * c;
      vd2[j] = (va1[2 * j] - va1[2 * j + 1]) * c;
      va2[j] = (va1[2 * j] + va1[2 * j + 1]) * c;
    }
    const float qd3 = (qa2[0] - qa2[1]) * c, qa3 = (qa2[0] + qa2[1]) * c;
    const float vd3 = (va2[0] - va2[1]) * c, va3 = (va2[0] + va2[1]) * c;

    const int wb = h * 192 + dh;
    const float wq0 = wq[wb], wq1 = wq[wb + 64], wq2 = wq[wb + 128];
    const float wv0 = wv[wb], wv1 = wv[wb + 64], wv2 = wv[wb + 128];

    const float pa = (qa3 * wq0) * (va3 * wv0);
    const float pd3 = (qd3 * wq1) * (vd3 * wv1);
    float pd2[2], pd1[4];
#pragma unroll
    for (int j = 0; j < 2; j++) pd2[j] = (qd2[j] * wq2) * (vd2[j] * wv2);
#pragma unroll
    for (int i = 0; i < 4; i++) pd1[i] = qd1[i] * vd1[i];

    float s2[2], s1[4];
    s2[0] = (pa + pd3) * c;
    s2[1] = (pa - pd3) * c;
#pragma unroll
    for (int j = 0; j < 2; j++) {
      s1[2 * j] = (s2[j] + pd2[j]) * c;
      s1[2 * j + 1] = (s2[j] - pd2[j]) * c;
    }
#pragma unroll
    for (int i = 0; i < 4; i++) {
      o[2 * i][dd] = (f16)((s1[i] + pd1[i]) * c);
      o[2 * i + 1][dd] = (f16)((s1[i] - pd1[i]) * c);
    }
  }
#pragma unroll
  for (int i = 0; i < 8; i++) *(f16x4*)(out + (m0 + i) * 1024 + d0) = o[i];
}

// ---------------- launch ----------------
extern "C" void kernel_launch(void* const* d_in, const int* in_sizes, int n_in,
                              void* d_out, int out_size, void* d_ws, size_t ws_size,
                              hipStream_t stream) {
  (void)in_sizes; (void)n_in; (void)out_size; (void)ws_size;
  const float* query = (const float*)d_in[0];
  const float* W_qkv = (const float*)d_in[1];
  const float* b_qkv = (const float*)d_in[2];
  const float* W_out = (const float*)d_in[3];
  const float* b_out = (const float*)d_in[4];
  const float* wq = (const float*)d_in[5];
  const float* wv = (const float*)d_in[6];
  float* out = (float*)d_out;

  // workspace layout
  char* ws = (char*)d_ws;
  f16* qf16 = (f16*)ws;                                // 67,108,864 B (reused as a_f16)
  f16* Wqv = (f16*)(ws + 67108864);                    //  4,194,304 B
  float* bqv = (float*)(ws + 67108864 + 4194304);      //      8,192 B
  f16* Wout = (f16*)(ws + 67108864 + 4194304 + 8192);  //  2,097,152 B
  f16* qv = (f16*)d_out;  // qv intermediate lives in d_out (exactly out bytes)
  f16* a_f16 = qf16;      // alias: qf16 dead after GEMM1

  // 1. query -> f16
  cvt_f32_f16_k<<<dim3(8388608 / 256), dim3(256), 0, stream>>>(query, qf16, 8388608);
  // 2. pack W_qv + bias
  pack_wqv_k<<<dim3(2048), dim3(256), 0, stream>>>(W_qkv, b_qkv, Wqv, bqv);
  // 3. W_out -> f16
  cvt_f32_f16_k<<<dim3(262144 / 256), dim3(256), 0, stream>>>(W_out, Wout, 262144);
  // 4. GEMM1: qv[32768,2048] = query_f16 * Wqv^T + bqv   (grid 1024 blocks)
  gemm256_k<f16><<<dim3((2048 / 256) * (32768 / 256)), dim3(256), 0, stream>>>(
      qf16, Wqv, bqv, qv, 32768, 2048, 1024, 2048 / 256);
  // 5. fused wavelet middle: a[32768,1024] f16
  dwt_middle_k<<<dim3(4096), dim3(256), 0, stream>>>(qv, wq, wv, a_f16);
  // 6. GEMM2: out = a * Wout^T + b_out (fp32)   (grid 512 blocks)
  gemm256_k<float><<<dim3((1024 / 256) * (32768 / 256)), dim3(256), 0, stream>>>(
      a_f16, Wout, b_out, out, 32768, 1024, 1024, 1024 / 256);
}

// Round 8
// 296.219 us; speedup vs baseline: 1.7584x; 1.0978x over previous
//
#include <hip/hip_runtime.h>
#include <hip/hip_fp16.h>
#include <cstdint>
#include <cstddef>

typedef _Float16 f16;
typedef __attribute__((ext_vector_type(4))) _Float16 f16x4;
typedef __attribute__((ext_vector_type(8))) _Float16 f16x8;
typedef __attribute__((ext_vector_type(4))) float f32x4;

#define C_INV_SQRT2 0.70710678118654752440f

__device__ __forceinline__ void gld_lds16(const void* g, void* l) {
  __builtin_amdgcn_global_load_lds((const __attribute__((address_space(1))) void*)g,
                                   (__attribute__((address_space(3))) void*)l, 16, 0, 0);
}

// ---------------- conversion kernels ----------------
__global__ __launch_bounds__(256) void cvt_f32_f16_k(const float* __restrict__ in,
                                                     f16* __restrict__ out, int n4) {
  int i = blockIdx.x * 256 + threadIdx.x;
  if (i >= n4) return;
  const float4 x = ((const float4*)in)[i];
  f16x4 y;
  y.x = (f16)x.x; y.y = (f16)x.y; y.z = (f16)x.z; y.w = (f16)x.w;
  ((f16x4*)out)[i] = y;
}

// pack W_qkv rows {0..1023} and {2048..3071} into Wo[2048][1024] f16; same for bias
__global__ __launch_bounds__(256) void pack_wqv_k(const float* __restrict__ W,
                                                  const float* __restrict__ b,
                                                  f16* __restrict__ Wo,
                                                  float* __restrict__ bo) {
  int i = blockIdx.x * 256 + threadIdx.x;
  int n = i >> 8;
  int c = (i & 255) * 4;
  int sn = (n < 1024) ? n : (n + 1024);
  const float4 x = *(const float4*)(W + (size_t)sn * 1024 + c);
  f16x4 y; y.x = (f16)x.x; y.y = (f16)x.y; y.z = (f16)x.z; y.w = (f16)x.w;
  *(f16x4*)(Wo + (size_t)n * 1024 + c) = y;
  if (i < 2048) bo[i] = b[(i < 1024) ? i : (i + 1024)];
}

// ---- 256x256 GEMM, 8 waves (2M x 4N), A-frag read-ahead pipeline ----
// C[M,N] = A[M,K]*B[N,K]^T + bias.  512 threads; per-wave output 128(M) x 64(N).
// Sub-tile BK=32; 4 LDS buffers (128 KiB); stage-ahead-3.
// LOAD LEDGER: each STAGE4 = 4 global_load_lds.  At top of ITER(s), outstanding
// = stages {s+1, s+2} = 8 loads.  We read B(s) AND A(s+1) after the barrier, so
// we must drain to vmcnt(4) (stage(s+1) landed; only stage(s+2) in flight).
// Prologue: 12 outstanding -> vmcnt(8) before reading A(0).   [R6 bug: vmcnt(16)
// was a no-op and vmcnt(8) left stage(s+1) in flight -> race -> absmax 0.298]
// ITER(s): vmcnt(4) -> barrier -> read B(s) (4 ds_read) -> read A(s+1) into
//   alternate set (8 ds_read) -> STAGE(s+3) -> 32 MFMA on {A(s), B(s)}.
//   First MFMA waits lgkmcnt(8) (B(s) done, in-order LDS returns); A(s+1)
//   service hides under the MFMA cluster.
// LDS chunk-XOR swizzle chunk^((row>>1)&3), both-sides (R3-verified 0 conflicts).
// T1 bijective XCD swizzle (nwg % 8 == 0).  T5 setprio around MFMA cluster.

#define STAGE4(bufi, k0)                          \
  {                                               \
    f16* LA = &lds[bufi][0][0];                   \
    f16* LB = &lds[bufi][1][0];                   \
    gld_lds16(pGA0 + (k0), LA + dst0);            \
    gld_lds16(pGA1 + (k0), LA + dst1);            \
    gld_lds16(pGB0 + (k0), LB + dst0);            \
    gld_lds16(pGB1 + (k0), LB + dst1);            \
  }

#define ITER(s, aC, aN)                                                       \
  {                                                                           \
    if ((s) <= NS - 3) {                                                      \
      asm volatile("s_waitcnt vmcnt(4)" ::: "memory");                        \
    } else if ((s) == NS - 2) {                                               \
      asm volatile("s_waitcnt vmcnt(0)" ::: "memory");                        \
    }                                                                         \
    __builtin_amdgcn_sched_barrier(0);                                        \
    __builtin_amdgcn_s_barrier();                                             \
    __builtin_amdgcn_sched_barrier(0);                                        \
    const f16* pBc = &lds[(s) & 3][1][0];                                     \
    f16x8 bF[4];                                                              \
    _Pragma("unroll") for (int nj = 0; nj < 4; nj++)                          \
        bF[nj] = *(const f16x8*)(pBc + offB[nj]);                             \
    if ((s) + 1 < NS) {                                                       \
      const f16* pAn = &lds[((s) + 1) & 3][0][0];                             \
      _Pragma("unroll") for (int mi = 0; mi < 8; mi++)                        \
          aN[mi] = *(const f16x8*)(pAn + offA[mi]);                           \
    }                                                                         \
    if ((s) + 3 < NS) STAGE4(((s) + 3) & 3, ((s) + 3) * 32);                  \
    __builtin_amdgcn_s_setprio(1);                                            \
    _Pragma("unroll") for (int mi = 0; mi < 8; mi++)                          \
        _Pragma("unroll") for (int nj = 0; nj < 4; nj++)                      \
            acc[mi][nj] = __builtin_amdgcn_mfma_f32_16x16x32_f16(             \
                aC[mi], bF[nj], acc[mi][nj], 0, 0, 0);                        \
    __builtin_amdgcn_s_setprio(0);                                            \
  }

template <typename CT>
__global__ __launch_bounds__(512, 2) void gemm256_k(const f16* __restrict__ A,
                                                    const f16* __restrict__ B,
                                                    const float* __restrict__ bias,
                                                    CT* __restrict__ C,
                                                    int M, int N, int K, int nbx) {
  __shared__ f16 lds[4][2][256 * 32];  // [buf][A/B][256 rows x 32 f16] = 128 KiB
  const int t = threadIdx.x;
  const int w = t >> 6, l = t & 63;
  const int wm = w >> 2, wn = w & 3;  // 2 x 4 wave grid
  const int hi = l >> 4, lo = l & 15;

  // T1: bijective XCD swizzle
  const int nwg = gridDim.x;
  const int cpx = nwg >> 3;
  const int bid = blockIdx.x;
  const int nid = (bid & 7) * cpx + (bid >> 3);
  const int by = nid / nbx, bx = nid - by * nbx;
  const int m0 = by * 256, n0 = bx * 256;

  const f16* GA = A + (size_t)m0 * K;
  const f16* GB = B + (size_t)n0 * K;

  // staging: thread covers 16B slots u = i*512 + t (i=0,1) of a [256 row][4 chunk]
  // plane; slot u holds global (row = u>>2, chunk = (u&3) ^ ((u>>3)&3))
  int rowS[2], chS[2];
#pragma unroll
  for (int i = 0; i < 2; i++) {
    const int u = i * 512 + t;
    rowS[i] = u >> 2;
    chS[i] = (u & 3) ^ ((u >> 3) & 3);
  }
  const f16* pGA0 = GA + (size_t)rowS[0] * K + chS[0] * 8;
  const f16* pGA1 = GA + (size_t)rowS[1] * K + chS[1] * 8;
  const f16* pGB0 = GB + (size_t)rowS[0] * K + chS[0] * 8;
  const f16* pGB1 = GB + (size_t)rowS[1] * K + chS[1] * 8;
  const int dst0 = (0 * 512 + w * 64) * 8;  // wave-uniform LDS dest (f16 units)
  const int dst1 = (1 * 512 + w * 64) * 8;

  // read-side swizzled fragment offsets (f16 units within one [256][32] plane)
  int offA[8], offB[4];
#pragma unroll
  for (int mi = 0; mi < 8; mi++) {
    const int r = wm * 128 + mi * 16 + lo;
    offA[mi] = r * 32 + ((hi ^ ((r >> 1) & 3)) << 3);
  }
#pragma unroll
  for (int nj = 0; nj < 4; nj++) {
    const int r = wn * 64 + nj * 16 + lo;
    offB[nj] = r * 32 + ((hi ^ ((r >> 1) & 3)) << 3);
  }

  f32x4 acc[8][4] = {};
  f16x8 aP[8], aQ[8];
  const int NS = K >> 5;  // K=1024 -> 32 (even)

  STAGE4(0, 0);
  STAGE4(1, 32);
  STAGE4(2, 64);
  // 12 loads outstanding; drain to 8 -> stage(0) landed everywhere after barrier
  asm volatile("s_waitcnt vmcnt(8)" ::: "memory");
  __builtin_amdgcn_s_barrier();
  __builtin_amdgcn_sched_barrier(0);
  {
    const f16* pA0 = &lds[0][0][0];
#pragma unroll
    for (int mi = 0; mi < 8; mi++) aP[mi] = *(const f16x8*)(pA0 + offA[mi]);
  }

  for (int s = 0; s < NS; s += 2) {
    ITER(s, aP, aQ);
    ITER(s + 1, aQ, aP);
  }

  // epilogue: C/D layout col = lane&15, row = (lane>>4)*4 + reg
#pragma unroll
  for (int mi = 0; mi < 8; mi++) {
#pragma unroll
    for (int nj = 0; nj < 4; nj++) {
      const int col = n0 + wn * 64 + nj * 16 + lo;
      const float bb = bias[col];
      const size_t base = (size_t)(m0 + wm * 128 + mi * 16 + hi * 4) * N + col;
#pragma unroll
      for (int r = 0; r < 4; r++) C[base + (size_t)r * N] = (CT)(acc[mi][nj][r] + bb);
    }
  }
}

// ---------------- fused wavelet middle (vectorized f16x4 loads) ----------------
// qv: [32768][2048] f16 (cols 0..1023 = q, 1024..2047 = v), out: [32768][1024] f16
__global__ __launch_bounds__(256) void dwt_middle_k(const f16* __restrict__ qv,
                                                    const float* __restrict__ wq,
                                                    const float* __restrict__ wv,
                                                    f16* __restrict__ out) {
  const int g = blockIdx.x;        // row-group (8 rows), 0..4095
  const int d0 = threadIdx.x * 4;  // 4 consecutive d per thread
  const size_t m0 = (size_t)g * 8;

  f16x4 qr[8], vr[8], o[8];
#pragma unroll
  for (int i = 0; i < 8; i++) {
    qr[i] = *(const f16x4*)(qv + (m0 + i) * 2048 + d0);
    vr[i] = *(const f16x4*)(qv + (m0 + i) * 2048 + 1024 + d0);
  }
  const float c = C_INV_SQRT2;
#pragma unroll
  for (int dd = 0; dd < 4; dd++) {
    const int d = d0 + dd;
    const int h = d >> 6, dh = d & 63;
    float q[8], v[8];
#pragma unroll
    for (int i = 0; i < 8; i++) { q[i] = (float)qr[i][dd]; v[i] = (float)vr[i][dd]; }

    float qa1[4], qd1[4], va1[4], vd1[4];
#pragma unroll
    for (int i = 0; i < 4; i++) {
      qd1[i] = (q[2 * i] - q[2 * i + 1]) * c;
      qa1[i] = (q[2 * i] + q[2 * i + 1]) * c;
      vd1[i] = (v[2 * i] - v[2 * i + 1]) * c;
      va1[i] = (v[2 * i] + v[2 * i + 1]) * c;
    }
    float qa2[2], qd2[2], va2[2], vd2[2];
#pragma unroll
    for (int j = 0; j < 2; j++) {
      qd2[j] = (qa1[2 * j] - qa1[2 * j + 1]) * c;
      qa2[j] = (qa1[2 * j] + qa1[2 * j + 1]) * c;
      vd2[j] = (va1[2 * j] - va1[2 * j + 1]) * c;
      va2[j] = (va1[2 * j] + va1[2 * j + 1]) * c;
    }
    const float qd3 = (qa2[0] - qa2[1]) * c, qa3 = (qa2[0] + qa2[1]) * c;
    const float vd3 = (va2[0] - va2[1]) * c, va3 = (va2[0] + va2[1]) * c;

    const int wb = h * 192 + dh;
    const float wq0 = wq[wb], wq1 = wq[wb + 64], wq2 = wq[wb + 128];
    const float wv0 = wv[wb], wv1 = wv[wb + 64], wv2 = wv[wb + 128];

    const float pa = (qa3 * wq0) * (va3 * wv0);
    const float pd3 = (qd3 * wq1) * (vd3 * wv1);
    float pd2[2], pd1[4];
#pragma unroll
    for (int j = 0; j < 2; j++) pd2[j] = (qd2[j] * wq2) * (vd2[j] * wv2);
#pragma unroll
    for (int i = 0; i < 4; i++) pd1[i] = qd1[i] * vd1[i];

    float s2[2], s1[4];
    s2[0] = (pa + pd3) * c;
    s2[1] = (pa - pd3) * c;
#pragma unroll
    for (int j = 0; j < 2; j++) {
      s1[2 * j] = (s2[j] + pd2[j]) * c;
      s1[2 * j + 1] = (s2[j] - pd2[j]) * c;
    }
#pragma unroll
    for (int i = 0; i < 4; i++) {
      o[2 * i][dd] = (f16)((s1[i] + pd1[i]) * c);
      o[2 * i + 1][dd] = (f16)((s1[i] - pd1[i]) * c);
    }
  }
#pragma unroll
  for (int i = 0; i < 8; i++) *(f16x4*)(out + (m0 + i) * 1024 + d0) = o[i];
}

// ---------------- launch ----------------
extern "C" void kernel_launch(void* const* d_in, const int* in_sizes, int n_in,
                              void* d_out, int out_size, void* d_ws, size_t ws_size,
                              hipStream_t stream) {
  (void)in_sizes; (void)n_in; (void)out_size; (void)ws_size;
  const float* query = (const float*)d_in[0];
  const float* W_qkv = (const float*)d_in[1];
  const float* b_qkv = (const float*)d_in[2];
  const float* W_out = (const float*)d_in[3];
  const float* b_out = (const float*)d_in[4];
  const float* wq = (const float*)d_in[5];
  const float* wv = (const float*)d_in[6];
  float* out = (float*)d_out;

  // workspace layout
  char* ws = (char*)d_ws;
  f16* qf16 = (f16*)ws;                                // 67,108,864 B (reused as a_f16)
  f16* Wqv = (f16*)(ws + 67108864);                    //  4,194,304 B
  float* bqv = (float*)(ws + 67108864 + 4194304);      //      8,192 B
  f16* Wout = (f16*)(ws + 67108864 + 4194304 + 8192);  //  2,097,152 B
  f16* qv = (f16*)d_out;  // qv intermediate lives in d_out (exactly out bytes)
  f16* a_f16 = qf16;      // alias: qf16 dead after GEMM1

  // 1. query -> f16
  cvt_f32_f16_k<<<dim3(8388608 / 256), dim3(256), 0, stream>>>(query, qf16, 8388608);
  // 2. pack W_qv + bias
  pack_wqv_k<<<dim3(2048), dim3(256), 0, stream>>>(W_qkv, b_qkv, Wqv, bqv);
  // 3. W_out -> f16
  cvt_f32_f16_k<<<dim3(262144 / 256), dim3(256), 0, stream>>>(W_out, Wout, 262144);
  // 4. GEMM1: qv[32768,2048] = query_f16 * Wqv^T + bqv   (grid 1024 blocks)
  gemm256_k<f16><<<dim3((2048 / 256) * (32768 / 256)), dim3(512), 0, stream>>>(
      qf16, Wqv, bqv, qv, 32768, 2048, 1024, 2048 / 256);
  // 5. fused wavelet middle: a[32768,1024] f16
  dwt_middle_k<<<dim3(4096), dim3(256), 0, stream>>>(qv, wq, wv, a_f16);
  // 6. GEMM2: out = a * Wout^T + b_out (fp32)   (grid 512 blocks)
  gemm256_k<float><<<dim3((1024 / 256) * (32768 / 256)), dim3(512), 0, stream>>>(
      a_f16, Wout, b_out, out, 32768, 1024, 1024, 1024 / 256);
}

// Round 9
// 286.148 us; speedup vs baseline: 1.8203x; 1.0352x over previous
//
#include <hip/hip_runtime.h>
#include <hip/hip_fp16.h>
#include <cstdint>
#include <cstddef>

typedef _Float16 f16;
typedef __attribute__((ext_vector_type(4))) _Float16 f16x4;
typedef __attribute__((ext_vector_type(8))) _Float16 f16x8;
typedef __attribute__((ext_vector_type(4))) float f32x4;

#define C_INV_SQRT2 0.70710678118654752440f

__device__ __forceinline__ void gld_lds16(const void* g, void* l) {
  __builtin_amdgcn_global_load_lds((const __attribute__((address_space(1))) void*)g,
                                   (__attribute__((address_space(3))) void*)l, 16, 0, 0);
}

// ---------------- conversion kernels ----------------
__global__ __launch_bounds__(256) void cvt_f32_f16_k(const float* __restrict__ in,
                                                     f16* __restrict__ out, int n4) {
  int i = blockIdx.x * 256 + threadIdx.x;
  if (i >= n4) return;
  const float4 x = ((const float4*)in)[i];
  f16x4 y;
  y.x = (f16)x.x; y.y = (f16)x.y; y.z = (f16)x.z; y.w = (f16)x.w;
  ((f16x4*)out)[i] = y;
}

// pack W_qkv rows {0..1023} and {2048..3071} into Wo[2048][1024] f16; same for bias
__global__ __launch_bounds__(256) void pack_wqv_k(const float* __restrict__ W,
                                                  const float* __restrict__ b,
                                                  f16* __restrict__ Wo,
                                                  float* __restrict__ bo) {
  int i = blockIdx.x * 256 + threadIdx.x;
  int n = i >> 8;
  int c = (i & 255) * 4;
  int sn = (n < 1024) ? n : (n + 1024);
  const float4 x = *(const float4*)(W + (size_t)sn * 1024 + c);
  f16x4 y; y.x = (f16)x.x; y.y = (f16)x.y; y.z = (f16)x.z; y.w = (f16)x.w;
  *(f16x4*)(Wo + (size_t)n * 1024 + c) = y;
  if (i < 2048) bo[i] = b[(i < 1024) ? i : (i + 1024)];
}

// ---- 256x256 GEMM, 8 waves (2M x 4N), m201-style 4-phase/K-tile schedule ----
// C[M,N] = A[M,K]*B[N,K]^T + bias.  512 threads; per-wave output 128(M) x 64(N).
// K-tile BK=64; LDS = 2 buf x {A,B} x 2 halves x [128 rows x 64 f16] = 128 KiB.
// Half-tile stage = 2 global_load_lds (512 thr x 16B x 2 = 16 KiB).
//
// STAGE SCHEDULE (tile x's halves staged at): Ah0,Ah1 @ (x-2).p2,p3 ;
//                                             Bh0,Bh1 @ (x-1).p0,p1.
// PHASES of tile t (buf = t&1):
//  p0: vmcnt(4) [tile-t halves landed; A(t+1) halves = 4 loads stay in flight]
//      -> barrier -> reads: A mi0-3 (8) + B all (8) -> stage Bh0(t+1) -> 16 MFMA (mi0,1)
//  p1: barrier -> reads A mi4-7 (8) -> stage Bh1(t+1) -> 16 MFMA (mi2,3)
//  p2: lgkmcnt(0) [all my tile-t reads RETURNED] -> barrier
//      -> stage Ah0(t+2) [overwrites Ah0(t): free, certified by barrier] -> MFMA (mi4,5)
//  p3: lgkmcnt(0) -> barrier -> stage Ah1(t+2) -> MFMA (mi6,7)
// vmcnt ledger @ t.p0: outstanding <= {Ah(t+1):4} after drain -> vmcnt(4); t=NT-1 -> 0.
// Front-loaded reads free LDS slots early => stage-to-use distance 3-6 phases.
//
// LDS swizzle (both-sides, rule 21): 64-f16 rows = 8 chunks of 16B;
//   chunk' = chunk ^ (row & 7)  -> frag ds_read_b128 is bank-conflict-free
//   (rows 0..7 cover all 32 banks; 16-row frag = 2-way = free).
// T1 bijective XCD swizzle (nwg % 8 == 0).  T5 setprio around MFMA clusters.

#define STAGEH(bufi, mat, half, k0)                                              \
  {                                                                              \
    f16* Ld = &lds[bufi][mat][half][0];                                          \
    const f16* Gp =                                                              \
        ((mat) ? GB : GA) + (size_t)((half) * 128 + srow) * K + (k0) + sch * 8;  \
    gld_lds16(Gp, Ld + (w * 64) * 8);                                            \
    gld_lds16(Gp + (size_t)64 * K, Ld + (4096 + w * 64 * 8));                    \
  }

#define MFMA_PH(mi0)                                                             \
  __builtin_amdgcn_s_setprio(1);                                                 \
  _Pragma("unroll") for (int mm = (mi0); mm < (mi0) + 2; mm++)                   \
      _Pragma("unroll") for (int nj = 0; nj < 4; nj++) {                         \
    acc[mm][nj] = __builtin_amdgcn_mfma_f32_16x16x32_f16(aF[mm][0], bF[nj][0],   \
                                                         acc[mm][nj], 0, 0, 0);  \
    acc[mm][nj] = __builtin_amdgcn_mfma_f32_16x16x32_f16(aF[mm][1], bF[nj][1],   \
                                                         acc[mm][nj], 0, 0, 0);  \
  }                                                                              \
  __builtin_amdgcn_s_setprio(0);

#define BAR_SEQ()                       \
  __builtin_amdgcn_sched_barrier(0);    \
  __builtin_amdgcn_s_barrier();         \
  __builtin_amdgcn_sched_barrier(0);

template <typename CT>
__global__ __launch_bounds__(512, 2) void gemm256_k(const f16* __restrict__ A,
                                                    const f16* __restrict__ B,
                                                    const float* __restrict__ bias,
                                                    CT* __restrict__ C,
                                                    int M, int N, int K, int nbx) {
  __shared__ f16 lds[2][2][2][128 * 64];  // [buf][A=0/B=1][half][128r x 64 f16] = 128 KiB
  const int t = threadIdx.x;
  const int w = t >> 6, l = t & 63;
  const int wm = w >> 2, wn = w & 3;  // 2 x 4 wave grid
  const int hi = l >> 4, lo = l & 15;

  // T1: bijective XCD swizzle
  const int nwg = gridDim.x;
  const int cpx = nwg >> 3;
  const int bid = blockIdx.x;
  const int nid = (bid & 7) * cpx + (bid >> 3);
  const int by = nid / nbx, bx = nid - by * nbx;
  const int m0 = by * 256, n0 = bx * 256;

  const f16* GA = A + (size_t)m0 * K;
  const f16* GB = B + (size_t)n0 * K;

  // staging: load i covers slot u = i*512 + t of 1024 slots per half-plane;
  // row = u>>3 (0..127), chunk = (u&7) ^ (row&7)  [inverse swizzle on source]
  const int srow = t >> 3;                       // 0..63 (load1 adds 64: (row&7) same)
  const int sch = (t & 7) ^ (srow & 7);

  // read-side per-lane swizzled column offsets (f16): chunk = kc*4+hi, ^ (lo&7)
  const int colk0 = ((hi ^ (lo & 7)) << 3);
  const int colk1 = (((4 | hi) ^ (lo & 7)) << 3);

  f32x4 acc[8][4] = {};
  f16x8 aF[8][2], bF[4][2];
  const int NT = K >> 6;  // K=1024 -> 16

  // prologue: A(0), B(0) into buf0; A(1) into buf1   (6 half-stages, 12 loads)
  STAGEH(0, 0, 0, 0); STAGEH(0, 0, 1, 0);
  STAGEH(0, 1, 0, 0); STAGEH(0, 1, 1, 0);
  STAGEH(1, 0, 0, 64); STAGEH(1, 0, 1, 64);

  for (int tt = 0; tt < NT; ++tt) {
    const int buf = tt & 1;
    const f16* pA = &lds[buf][0][wm][0] + lo * 64;
    const f16* pB = &lds[buf][1][wn >> 1][0] + (wn & 1) * 4096 + lo * 64;
    const f16* pA0 = pA + colk0;
    const f16* pA1 = pA + colk1;
    const f16* pB0 = pB + colk0;
    const f16* pB1 = pB + colk1;

    // ---------------- phase 0
    if (tt < NT - 1) {
      asm volatile("s_waitcnt vmcnt(4)" ::: "memory");
    } else {
      asm volatile("s_waitcnt vmcnt(0)" ::: "memory");
    }
    BAR_SEQ();
    aF[0][0] = *(const f16x8*)(pA0 + 0 * 1024);
    aF[0][1] = *(const f16x8*)(pA1 + 0 * 1024);
    aF[1][0] = *(const f16x8*)(pA0 + 1 * 1024);
    aF[1][1] = *(const f16x8*)(pA1 + 1 * 1024);
#pragma unroll
    for (int nj = 0; nj < 4; nj++) {
      bF[nj][0] = *(const f16x8*)(pB0 + nj * 1024);
      bF[nj][1] = *(const f16x8*)(pB1 + nj * 1024);
    }
    aF[2][0] = *(const f16x8*)(pA0 + 2 * 1024);
    aF[2][1] = *(const f16x8*)(pA1 + 2 * 1024);
    aF[3][0] = *(const f16x8*)(pA0 + 3 * 1024);
    aF[3][1] = *(const f16x8*)(pA1 + 3 * 1024);
    if (tt + 1 < NT) STAGEH(buf ^ 1, 1, 0, (tt + 1) * 64);
    MFMA_PH(0);

    // ---------------- phase 1
    BAR_SEQ();
#pragma unroll
    for (int mi = 4; mi < 8; mi++) {
      aF[mi][0] = *(const f16x8*)(pA0 + mi * 1024);
      aF[mi][1] = *(const f16x8*)(pA1 + mi * 1024);
    }
    if (tt + 1 < NT) STAGEH(buf ^ 1, 1, 1, (tt + 1) * 64);
    MFMA_PH(2);

    // ---------------- phase 2 (reads of tile tt must be RETURNED before
    // overwriting Ah0: lgkm drain, then barrier certifies chip-wide)
    asm volatile("s_waitcnt lgkmcnt(0)" ::: "memory");
    BAR_SEQ();
    if (tt + 2 < NT) STAGEH(buf, 0, 0, (tt + 2) * 64);
    MFMA_PH(4);

    // ---------------- phase 3
    asm volatile("s_waitcnt lgkmcnt(0)" ::: "memory");
    BAR_SEQ();
    if (tt + 2 < NT) STAGEH(buf, 0, 1, (tt + 2) * 64);
    MFMA_PH(6);
  }

  // epilogue: C/D layout col = lane&15, row = (lane>>4)*4 + reg
#pragma unroll
  for (int mi = 0; mi < 8; mi++) {
#pragma unroll
    for (int nj = 0; nj < 4; nj++) {
      const int col = n0 + wn * 64 + nj * 16 + lo;
      const float bb = bias[col];
      const size_t base = (size_t)(m0 + wm * 128 + mi * 16 + hi * 4) * N + col;
#pragma unroll
      for (int r = 0; r < 4; r++) C[base + (size_t)r * N] = (CT)(acc[mi][nj][r] + bb);
    }
  }
}

// ---------------- fused wavelet middle (vectorized f16x4 loads) ----------------
// qv: [32768][2048] f16 (cols 0..1023 = q, 1024..2047 = v), out: [32768][1024] f16
__global__ __launch_bounds__(256) void dwt_middle_k(const f16* __restrict__ qv,
                                                    const float* __restrict__ wq,
                                                    const float* __restrict__ wv,
                                                    f16* __restrict__ out) {
  const int g = blockIdx.x;        // row-group (8 rows), 0..4095
  const int d0 = threadIdx.x * 4;  // 4 consecutive d per thread
  const size_t m0 = (size_t)g * 8;

  f16x4 qr[8], vr[8], o[8];
#pragma unroll
  for (int i = 0; i < 8; i++) {
    qr[i] = *(const f16x4*)(qv + (m0 + i) * 2048 + d0);
    vr[i] = *(const f16x4*)(qv + (m0 + i) * 2048 + 1024 + d0);
  }
  const float c = C_INV_SQRT2;
#pragma unroll
  for (int dd = 0; dd < 4; dd++) {
    const int d = d0 + dd;
    const int h = d >> 6, dh = d & 63;
    float q[8], v[8];
#pragma unroll
    for (int i = 0; i < 8; i++) { q[i] = (float)qr[i][dd]; v[i] = (float)vr[i][dd]; }

    float qa1[4], qd1[4], va1[4], vd1[4];
#pragma unroll
    for (int i = 0; i < 4; i++) {
      qd1[i] = (q[2 * i] - q[2 * i + 1]) * c;
      qa1[i] = (q[2 * i] + q[2 * i + 1]) * c;
      vd1[i] = (v[2 * i] - v[2 * i + 1]) * c;
      va1[i] = (v[2 * i] + v[2 * i + 1]) * c;
    }
    float qa2[2], qd2[2], va2[2], vd2[2];
#pragma unroll
    for (int j = 0; j < 2; j++) {
      qd2[j] = (qa1[2 * j] - qa1[2 * j + 1]) * c;
      qa2[j] = (qa1[2 * j] + qa1[2 * j + 1]) * c;
      vd2[j] = (va1[2 * j] - va1[2 * j + 1]) * c;
      va2[j] = (va1[2 * j] + va1[2 * j + 1]) * c;
    }
    const float qd3 = (qa2[0] - qa2[1]) * c, qa3 = (qa2[0] + qa2[1]) * c;
    const float vd3 = (va2[0] - va2[1]) * c, va3 = (va2[0] + va2[1]) * c;

    const int wb = h * 192 + dh;
    const float wq0 = wq[wb], wq1 = wq[wb + 64], wq2 = wq[wb + 128];
    const float wv0 = wv[wb], wv1 = wv[wb + 64], wv2 = wv[wb + 128];

    const float pa = (qa3 * wq0) * (va3 * wv0);
    const float pd3 = (qd3 * wq1) * (vd3 * wv1);
    float pd2[2], pd1[4];
#pragma unroll
    for (int j = 0; j < 2; j++) pd2[j] = (qd2[j] * wq2) * (vd2[j] * wv2);
#pragma unroll
    for (int i = 0; i < 4; i++) pd1[i] = qd1[i] * vd1[i];

    float s2[2], s1[4];
    s2[0] = (pa + pd3) * c;
    s2[1] = (pa - pd3) * c;
#pragma unroll
    for (int j = 0; j < 2; j++) {
      s1[2 * j] = (s2[j] + pd2[j]) * c;
      s1[2 * j + 1] = (s2[j] - pd2[j]) * c;
    }
#pragma unroll
    for (int i = 0; i < 4; i++) {
      o[2 * i][dd] = (f16)((s1[i] + pd1[i]) * c);
      o[2 * i + 1][dd] = (f16)((s1[i] - pd1[i]) * c);
    }
  }
#pragma unroll
  for (int i = 0; i < 8; i++) *(f16x4*)(out + (m0 + i) * 1024 + d0) = o[i];
}

// ---------------- launch ----------------
extern "C" void kernel_launch(void* const* d_in, const int* in_sizes, int n_in,
                              void* d_out, int out_size, void* d_ws, size_t ws_size,
                              hipStream_t stream) {
  (void)in_sizes; (void)n_in; (void)out_size; (void)ws_size;
  const float* query = (const float*)d_in[0];
  const float* W_qkv = (const float*)d_in[1];
  const float* b_qkv = (const float*)d_in[2];
  const float* W_out = (const float*)d_in[3];
  const float* b_out = (const float*)d_in[4];
  const float* wq = (const float*)d_in[5];
  const float* wv = (const float*)d_in[6];
  float* out = (float*)d_out;

  // workspace layout
  char* ws = (char*)d_ws;
  f16* qf16 = (f16*)ws;                                // 67,108,864 B (reused as a_f16)
  f16* Wqv = (f16*)(ws + 67108864);                    //  4,194,304 B
  float* bqv = (float*)(ws + 67108864 + 4194304);      //      8,192 B
  f16* Wout = (f16*)(ws + 67108864 + 4194304 + 8192);  //  2,097,152 B
  f16* qv = (f16*)d_out;  // qv intermediate lives in d_out (exactly out bytes)
  f16* a_f16 = qf16;      // alias: qf16 dead after GEMM1

  // 1. query -> f16
  cvt_f32_f16_k<<<dim3(8388608 / 256), dim3(256), 0, stream>>>(query, qf16, 8388608);
  // 2. pack W_qv + bias
  pack_wqv_k<<<dim3(2048), dim3(256), 0, stream>>>(W_qkv, b_qkv, Wqv, bqv);
  // 3. W_out -> f16
  cvt_f32_f16_k<<<dim3(262144 / 256), dim3(256), 0, stream>>>(W_out, Wout, 262144);
  // 4. GEMM1: qv[32768,2048] = query_f16 * Wqv^T + bqv   (grid 1024 blocks)
  gemm256_k<f16><<<dim3((2048 / 256) * (32768 / 256)), dim3(512), 0, stream>>>(
      qf16, Wqv, bqv, qv, 32768, 2048, 1024, 2048 / 256);
  // 5. fused wavelet middle: a[32768,1024] f16
  dwt_middle_k<<<dim3(4096), dim3(256), 0, stream>>>(qv, wq, wv, a_f16);
  // 6. GEMM2: out = a * Wout^T + b_out (fp32)   (grid 512 blocks)
  gemm256_k<float><<<dim3((1024 / 256) * (32768 / 256)), dim3(512), 0, stream>>>(
      a_f16, Wout, b_out, out, 32768, 1024, 1024, 1024 / 256);
}

// Round 10
// 263.237 us; speedup vs baseline: 1.9787x; 1.0870x over previous
//
#include <hip/hip_runtime.h>
#include <hip/hip_fp16.h>
#include <cstdint>
#include <cstddef>

typedef _Float16 f16;
typedef __attribute__((ext_vector_type(4))) _Float16 f16x4;
typedef __attribute__((ext_vector_type(8))) _Float16 f16x8;
typedef __attribute__((ext_vector_type(4))) float f32x4;

#define C_INV_SQRT2 0.70710678118654752440f

__device__ __forceinline__ void gld_lds16(const void* g, void* l) {
  __builtin_amdgcn_global_load_lds((const __attribute__((address_space(1))) void*)g,
                                   (__attribute__((address_space(3))) void*)l, 16, 0, 0);
}

// ---------------- conversion kernels ----------------
__global__ __launch_bounds__(256) void cvt_f32_f16_k(const float* __restrict__ in,
                                                     f16* __restrict__ out, int n4) {
  int i = blockIdx.x * 256 + threadIdx.x;
  if (i >= n4) return;
  const float4 x = ((const float4*)in)[i];
  f16x4 y;
  y.x = (f16)x.x; y.y = (f16)x.y; y.z = (f16)x.z; y.w = (f16)x.w;
  ((f16x4*)out)[i] = y;
}

// pack W_qkv rows {0..1023} and {2048..3071} into Wo[2048][1024] f16; same for bias
__global__ __launch_bounds__(256) void pack_wqv_k(const float* __restrict__ W,
                                                  const float* __restrict__ b,
                                                  f16* __restrict__ Wo,
                                                  float* __restrict__ bo) {
  int i = blockIdx.x * 256 + threadIdx.x;
  int n = i >> 8;
  int c = (i & 255) * 4;
  int sn = (n < 1024) ? n : (n + 1024);
  const float4 x = *(const float4*)(W + (size_t)sn * 1024 + c);
  f16x4 y; y.x = (f16)x.x; y.y = (f16)x.y; y.z = (f16)x.z; y.w = (f16)x.w;
  *(f16x4*)(Wo + (size_t)n * 1024 + c) = y;
  if (i < 2048) bo[i] = b[(i < 1024) ? i : (i + 1024)];
}

// -------- 3-level Haar forward + weighted product + inverse, 8 samples --------
__device__ __forceinline__ void haar_mid(const f16x8 q8, const f16x8 v8,
                                         float wq0, float wq1, float wq2,
                                         float wv0, float wv1, float wv2,
                                         float* a8) {
  const float c = C_INV_SQRT2;
  float q[8], v[8];
#pragma unroll
  for (int i = 0; i < 8; i++) { q[i] = (float)q8[i]; v[i] = (float)v8[i]; }
  float qa1[4], qd1[4], va1[4], vd1[4];
#pragma unroll
  for (int i = 0; i < 4; i++) {
    qd1[i] = (q[2 * i] - q[2 * i + 1]) * c;
    qa1[i] = (q[2 * i] + q[2 * i + 1]) * c;
    vd1[i] = (v[2 * i] - v[2 * i + 1]) * c;
    va1[i] = (v[2 * i] + v[2 * i + 1]) * c;
  }
  float qa2[2], qd2[2], va2[2], vd2[2];
#pragma unroll
  for (int j = 0; j < 2; j++) {
    qd2[j] = (qa1[2 * j] - qa1[2 * j + 1]) * c;
    qa2[j] = (qa1[2 * j] + qa1[2 * j + 1]) * c;
    vd2[j] = (va1[2 * j] - va1[2 * j + 1]) * c;
    va2[j] = (va1[2 * j] + va1[2 * j + 1]) * c;
  }
  const float qd3 = (qa2[0] - qa2[1]) * c, qa3 = (qa2[0] + qa2[1]) * c;
  const float vd3 = (va2[0] - va2[1]) * c, va3 = (va2[0] + va2[1]) * c;
  const float pa = (qa3 * wq0) * (va3 * wv0);
  const float pd3 = (qd3 * wq1) * (vd3 * wv1);
  float pd2[2], pd1[4];
#pragma unroll
  for (int j = 0; j < 2; j++) pd2[j] = (qd2[j] * wq2) * (vd2[j] * wv2);
#pragma unroll
  for (int i = 0; i < 4; i++) pd1[i] = qd1[i] * vd1[i];
  float s2[2], s1[4];
  s2[0] = (pa + pd3) * c;
  s2[1] = (pa - pd3) * c;
#pragma unroll
  for (int j = 0; j < 2; j++) {
    s1[2 * j] = (s2[j] + pd2[j]) * c;
    s1[2 * j + 1] = (s2[j] - pd2[j]) * c;
  }
#pragma unroll
  for (int i = 0; i < 4; i++) {
    a8[2 * i] = (s1[i] + pd1[i]) * c;
    a8[2 * i + 1] = (s1[i] - pd1[i]) * c;
  }
}

// ---- 256x256 GEMM, 8 waves (2M x 4N), R8 4-phase/K-tile schedule ----
// FUSED=true: B panel = W rows {d0..d0+127} U {1024+d0..+127}; epilogue runs the
// Haar middle via transposed XOR-swizzled LDS c-tile and writes a[M][1024] f16.
// FUSED=false: plain C = A*B^T + bias (R8-verified).
// Schedule/sync/swizzle identical to R8 (load ledger unchanged).

#define STAGEH(bufi, mat, half, Gbase, k0)                         \
  {                                                                \
    f16* Ld = &lds[bufi][mat][half][0];                            \
    const f16* Gp = (Gbase) + (size_t)srow * K + (k0) + sch * 8;   \
    gld_lds16(Gp, Ld + (w * 64) * 8);                              \
    gld_lds16(Gp + (size_t)64 * K, Ld + (4096 + w * 64 * 8));      \
  }

#define MFMA_PH(mi0)                                                             \
  __builtin_amdgcn_s_setprio(1);                                                 \
  _Pragma("unroll") for (int mm = (mi0); mm < (mi0) + 2; mm++)                   \
      _Pragma("unroll") for (int nj = 0; nj < 4; nj++) {                         \
    acc[mm][nj] = __builtin_amdgcn_mfma_f32_16x16x32_f16(aF[mm][0], bF[nj][0],   \
                                                         acc[mm][nj], 0, 0, 0);  \
    acc[mm][nj] = __builtin_amdgcn_mfma_f32_16x16x32_f16(aF[mm][1], bF[nj][1],   \
                                                         acc[mm][nj], 0, 0, 0);  \
  }                                                                              \
  __builtin_amdgcn_s_setprio(0);

#define BAR_SEQ()                       \
  __builtin_amdgcn_sched_barrier(0);    \
  __builtin_amdgcn_s_barrier();         \
  __builtin_amdgcn_sched_barrier(0);

template <typename CT, bool FUSED>
__global__ __launch_bounds__(512, 2) void gemm256_k(const f16* __restrict__ A,
                                                    const f16* __restrict__ B,
                                                    const float* __restrict__ bias,
                                                    CT* __restrict__ C,
                                                    const float* __restrict__ wq,
                                                    const float* __restrict__ wv,
                                                    int M, int N, int K, int nbx) {
  __shared__ f16 lds[2][2][2][128 * 64];  // 128 KiB
  const int t = threadIdx.x;
  const int w = t >> 6, l = t & 63;
  const int wm = w >> 2, wn = w & 3;  // 2 x 4 wave grid
  const int hi = l >> 4, lo = l & 15;

  // T1: bijective XCD swizzle (nwg % 8 == 0)
  const int nwg = gridDim.x;
  const int cpx = nwg >> 3;
  const int bid = blockIdx.x;
  const int nid = (bid & 7) * cpx + (bid >> 3);
  const int by = nid / nbx, bx = nid - by * nbx;
  const int m0 = by * 256;
  const int n0 = bx * 256;   // non-fused col base
  const int d0 = bx * 128;   // fused dim base

  const f16* GA = A + (size_t)m0 * K;
  const f16* GBq = FUSED ? (B + (size_t)d0 * K) : (B + (size_t)n0 * K);
  const f16* GBv = FUSED ? (B + (size_t)(1024 + d0) * K) : (GBq + (size_t)128 * K);

  // staging: load i covers slot u = i*512 + t per half-plane;
  // row = u>>3, chunk = (u&7) ^ (row&7)  [inverse swizzle on source]
  const int srow = t >> 3;
  const int sch = (t & 7) ^ (srow & 7);

  const int colk0 = ((hi ^ (lo & 7)) << 3);
  const int colk1 = (((4 | hi) ^ (lo & 7)) << 3);

  f32x4 acc[8][4] = {};
  f16x8 aF[8][2], bF[4][2];
  const int NT = K >> 6;  // 16

  // prologue: A(0), B(0) into buf0; A(1) into buf1   (12 loads)
  STAGEH(0, 0, 0, GA, 0); STAGEH(0, 0, 1, GA + (size_t)128 * K, 0);
  STAGEH(0, 1, 0, GBq, 0); STAGEH(0, 1, 1, GBv, 0);
  STAGEH(1, 0, 0, GA, 64); STAGEH(1, 0, 1, GA + (size_t)128 * K, 64);

  for (int tt = 0; tt < NT; ++tt) {
    const int buf = tt & 1;
    const f16* pA = &lds[buf][0][wm][0] + lo * 64;
    const f16* pB = &lds[buf][1][wn >> 1][0] + (wn & 1) * 4096 + lo * 64;
    const f16* pA0 = pA + colk0;
    const f16* pA1 = pA + colk1;
    const f16* pB0 = pB + colk0;
    const f16* pB1 = pB + colk1;

    // phase 0
    if (tt < NT - 1) {
      asm volatile("s_waitcnt vmcnt(4)" ::: "memory");
    } else {
      asm volatile("s_waitcnt vmcnt(0)" ::: "memory");
    }
    BAR_SEQ();
    aF[0][0] = *(const f16x8*)(pA0 + 0 * 1024);
    aF[0][1] = *(const f16x8*)(pA1 + 0 * 1024);
    aF[1][0] = *(const f16x8*)(pA0 + 1 * 1024);
    aF[1][1] = *(const f16x8*)(pA1 + 1 * 1024);
#pragma unroll
    for (int nj = 0; nj < 4; nj++) {
      bF[nj][0] = *(const f16x8*)(pB0 + nj * 1024);
      bF[nj][1] = *(const f16x8*)(pB1 + nj * 1024);
    }
    aF[2][0] = *(const f16x8*)(pA0 + 2 * 1024);
    aF[2][1] = *(const f16x8*)(pA1 + 2 * 1024);
    aF[3][0] = *(const f16x8*)(pA0 + 3 * 1024);
    aF[3][1] = *(const f16x8*)(pA1 + 3 * 1024);
    if (tt + 1 < NT) STAGEH(buf ^ 1, 1, 0, GBq, (tt + 1) * 64);
    MFMA_PH(0);

    // phase 1
    BAR_SEQ();
#pragma unroll
    for (int mi = 4; mi < 8; mi++) {
      aF[mi][0] = *(const f16x8*)(pA0 + mi * 1024);
      aF[mi][1] = *(const f16x8*)(pA1 + mi * 1024);
    }
    if (tt + 1 < NT) STAGEH(buf ^ 1, 1, 1, GBv, (tt + 1) * 64);
    MFMA_PH(2);

    // phase 2
    asm volatile("s_waitcnt lgkmcnt(0)" ::: "memory");
    BAR_SEQ();
    if (tt + 2 < NT) STAGEH(buf, 0, 0, GA, (tt + 2) * 64);
    MFMA_PH(4);

    // phase 3
    asm volatile("s_waitcnt lgkmcnt(0)" ::: "memory");
    BAR_SEQ();
    if (tt + 2 < NT) STAGEH(buf, 0, 1, GA + (size_t)128 * K, (tt + 2) * 64);
    MFMA_PH(6);
  }

  if (!FUSED) {
    // plain epilogue: C/D layout col = lane&15, row = (lane>>4)*4 + reg
#pragma unroll
    for (int mi = 0; mi < 8; mi++) {
#pragma unroll
      for (int nj = 0; nj < 4; nj++) {
        const int col = n0 + wn * 64 + nj * 16 + lo;
        const float bb = bias[col];
        const size_t base = (size_t)(m0 + wm * 128 + mi * 16 + hi * 4) * N + col;
#pragma unroll
        for (int r = 0; r < 4; r++) C[base + (size_t)r * N] = (CT)(acc[mi][nj][r] + bb);
      }
    }
  } else {
    // fused Haar-middle epilogue.
    // 1) dump acc+bias into transposed LDS c-tile ct[col][m] (f16), XOR-swizzled:
    //    byte = (col*512 + m*2) ^ ((col&7)<<4).  b64 writes, conflict-free.
    char* ctb = (char*)&lds[0][0][0][0];  // 256*256*2 = 128 KiB, LDS is dead now
#pragma unroll
    for (int mi = 0; mi < 8; mi++) {
#pragma unroll
      for (int nj = 0; nj < 4; nj++) {
        const int col = wn * 64 + nj * 16 + lo;  // tile col 0..255
        const int bidx = (col < 128) ? (d0 + col) : (1024 + d0 + col - 128);
        const float bb = bias[bidx];
        f16x4 y;
#pragma unroll
        for (int r = 0; r < 4; r++) y[r] = (f16)(acc[mi][nj][r] + bb);
        const int row2 = (wm * 128 + mi * 16 + hi * 4) * 2;
        const int byte = (col * 512 + row2) ^ ((col & 7) << 4);
        *(f16x4*)(ctb + byte) = y;
      }
    }
    asm volatile("s_waitcnt lgkmcnt(0)" ::: "memory");
    __builtin_amdgcn_s_barrier();
    // 2) per (dim c, 8-row group g): q8/v8 via ds_read_b128, Haar, store a.
#pragma unroll 1
    for (int p = 0; p < 8; ++p) {
      const int c = t & 127;            // dim within tile
      const int g = p * 4 + (t >> 7);   // row group 0..31
      const int byq = (c * 512 + g * 16) ^ ((c & 7) << 4);
      const f16x8 q8 = *(const f16x8*)(ctb + byq);
      const f16x8 v8 = *(const f16x8*)(ctb + byq + 65536);  // col c+128, same swz
      const int d = d0 + c;
      const int wb = (d >> 6) * 192 + (d & 63);
      float a8[8];
      haar_mid(q8, v8, wq[wb], wq[wb + 64], wq[wb + 128],
               wv[wb], wv[wb + 64], wv[wb + 128], a8);
      const size_t rb = (size_t)(m0 + g * 8) * 1024 + d;
#pragma unroll
      for (int i = 0; i < 8; i++) C[rb + (size_t)i * 1024] = (CT)a8[i];
    }
  }
}

// ---------------- standalone wavelet middle (ws-fallback path) ----------------
__global__ __launch_bounds__(256) void dwt_middle_k(const f16* __restrict__ qv,
                                                    const float* __restrict__ wq,
                                                    const float* __restrict__ wv,
                                                    f16* __restrict__ out) {
  const int g = blockIdx.x;
  const int d0 = threadIdx.x * 4;
  const size_t m0 = (size_t)g * 8;
  f16x4 qr[8], vr[8], o[8];
#pragma unroll
  for (int i = 0; i < 8; i++) {
    qr[i] = *(const f16x4*)(qv + (m0 + i) * 2048 + d0);
    vr[i] = *(const f16x4*)(qv + (m0 + i) * 2048 + 1024 + d0);
  }
#pragma unroll
  for (int dd = 0; dd < 4; dd++) {
    const int d = d0 + dd;
    const int wb = (d >> 6) * 192 + (d & 63);
    f16x8 q8, v8;
#pragma unroll
    for (int i = 0; i < 8; i++) { q8[i] = qr[i][dd]; v8[i] = vr[i][dd]; }
    float a8[8];
    haar_mid(q8, v8, wq[wb], wq[wb + 64], wq[wb + 128],
             wv[wb], wv[wb + 64], wv[wb + 128], a8);
#pragma unroll
    for (int i = 0; i < 8; i++) o[i][dd] = (f16)a8[i];
  }
#pragma unroll
  for (int i = 0; i < 8; i++) *(f16x4*)(out + (m0 + i) * 1024 + d0) = o[i];
}

// ---------------- launch ----------------
extern "C" void kernel_launch(void* const* d_in, const int* in_sizes, int n_in,
                              void* d_out, int out_size, void* d_ws, size_t ws_size,
                              hipStream_t stream) {
  (void)in_sizes; (void)n_in; (void)out_size;
  const float* query = (const float*)d_in[0];
  const float* W_qkv = (const float*)d_in[1];
  const float* b_qkv = (const float*)d_in[2];
  const float* W_out = (const float*)d_in[3];
  const float* b_out = (const float*)d_in[4];
  const float* wq = (const float*)d_in[5];
  const float* wv = (const float*)d_in[6];
  float* out = (float*)d_out;

  // workspace layout
  char* ws = (char*)d_ws;
  f16* qf16 = (f16*)ws;                                // 67,108,864 B
  f16* Wqv = (f16*)(ws + 67108864);                    //  4,194,304 B
  float* bqv = (float*)(ws + 67108864 + 4194304);      //      8,192 B
  f16* Wout = (f16*)(ws + 67108864 + 4194304 + 8192);  //  2,097,152 B
  const size_t OFS_A = 67108864UL + 4194304 + 8192 + 2097152;  // 73,408,512
  const size_t NEED = OFS_A + 67108864UL;                      // 140,517,376

  cvt_f32_f16_k<<<dim3(8388608 / 256), dim3(256), 0, stream>>>(query, qf16, 8388608);
  pack_wqv_k<<<dim3(2048), dim3(256), 0, stream>>>(W_qkv, b_qkv, Wqv, bqv);
  cvt_f32_f16_k<<<dim3(262144 / 256), dim3(256), 0, stream>>>(W_out, Wout, 262144);

  if (ws_size >= NEED) {
    // fused path: GEMM1 + Haar middle in epilogue -> a in ws; no qv, no middle kernel
    f16* a_f16 = (f16*)(ws + OFS_A);
    gemm256_k<f16, true><<<dim3(8 * 128), dim3(512), 0, stream>>>(
        qf16, Wqv, bqv, a_f16, wq, wv, 32768, 1024, 1024, 8);
    gemm256_k<float, false><<<dim3(4 * 128), dim3(512), 0, stream>>>(
        a_f16, Wout, b_out, out, nullptr, nullptr, 32768, 1024, 1024, 4);
  } else {
    // fallback (R8-verified): qv in d_out, a aliases qf16
    f16* qv = (f16*)d_out;
    f16* a_f16 = qf16;
    gemm256_k<f16, false><<<dim3(8 * 128), dim3(512), 0, stream>>>(
        qf16, Wqv, bqv, qv, nullptr, nullptr, 32768, 2048, 1024, 8);
    dwt_middle_k<<<dim3(4096), dim3(256), 0, stream>>>(qv, wq, wv, a_f16);
    gemm256_k<float, false><<<dim3(4 * 128), dim3(512), 0, stream>>>(
        a_f16, Wout, b_out, out, nullptr, nullptr, 32768, 1024, 1024, 4);
  }
}